// Round 1
// baseline (1472.903 us; speedup 1.0000x reference)
//
#include <hip/hip_runtime.h>

#define N_NODES_C 200000
#define N_EDGES_C 3200000
#define NUM_GRAPHS_C 1024

// ---------------- CSR build ----------------
__global__ __launch_bounds__(256) void k_deg(const int* __restrict__ dst, int* __restrict__ deg, int E){
  int e = blockIdx.x*256 + threadIdx.x;
  if (e < E) atomicAdd(&deg[dst[e]], 1);
}

__global__ __launch_bounds__(256) void k_scan1(const int* __restrict__ deg, int* __restrict__ tmp,
                                               int* __restrict__ bsum, int n){
  __shared__ int s[256];
  int i = blockIdx.x*256 + threadIdx.x;
  int v = (i < n) ? deg[i] : 0;
  s[threadIdx.x] = v;
  __syncthreads();
  #pragma unroll
  for (int off = 1; off < 256; off <<= 1){
    int t = (threadIdx.x >= (unsigned)off) ? s[threadIdx.x - off] : 0;
    __syncthreads();
    s[threadIdx.x] += t;
    __syncthreads();
  }
  if (i < n) tmp[i] = s[threadIdx.x];
  if (threadIdx.x == 255) bsum[blockIdx.x] = s[255];
}

__global__ __launch_bounds__(1024) void k_scan2(const int* __restrict__ bsum, int* __restrict__ bofs, int nb){
  __shared__ int s[1024];
  int t = threadIdx.x;
  int v = (t < nb) ? bsum[t] : 0;
  s[t] = v;
  __syncthreads();
  #pragma unroll
  for (int off = 1; off < 1024; off <<= 1){
    int u = (t >= off) ? s[t - off] : 0;
    __syncthreads();
    s[t] += u;
    __syncthreads();
  }
  if (t < nb) bofs[t] = s[t] - v;   // exclusive block offset
}

__global__ __launch_bounds__(256) void k_scan3(const int* __restrict__ tmp, const int* __restrict__ bofs,
                                               int* __restrict__ rowptr, int n){
  int i = blockIdx.x*256 + threadIdx.x;
  if (i < n) rowptr[i+1] = tmp[i] + bofs[blockIdx.x];
  if (i == 0) rowptr[0] = 0;
}

__global__ __launch_bounds__(256) void k_scatter(const int* __restrict__ src, const int* __restrict__ dst,
                                                 const int* __restrict__ rowptr, int* __restrict__ fill,
                                                 int* __restrict__ colb, int E){
  int e = blockIdx.x*256 + threadIdx.x;
  if (e < E){
    int d = dst[e];
    int pos = rowptr[d] + atomicAdd(&fill[d], 1);
    colb[pos] = src[e];
  }
}

// ---------------- node embedding ----------------
__global__ __launch_bounds__(256) void k_embed(const int* __restrict__ x, const float* __restrict__ emb,
                                               float* __restrict__ h, int total){
  int idx = blockIdx.x*256 + threadIdx.x;
  if (idx < total){
    int node = idx >> 6;
    h[idx] = emb[x[node]*64 + (idx & 63)];
  }
}

// ---------------- gather: z[i] = h[i] + sum_{j in N(i)} h[j] ----------------
// wave per node, lane = channel; 8 independent predicated loads in flight.
__global__ __launch_bounds__(256) void k_gather(const float* __restrict__ hin, const int* __restrict__ rowptr,
                                                const int* __restrict__ colb, float* __restrict__ zout, int n){
  int wid  = __builtin_amdgcn_readfirstlane((int)(threadIdx.x >> 6));
  int lane = threadIdx.x & 63;
  int i = blockIdx.x*4 + wid;
  if (i >= n) return;
  int rs = rowptr[i], re = rowptr[i+1];      // uniform -> s_load
  float acc = hin[i*64 + lane];
  float a0=0,a1=0,a2=0,a3=0,a4=0,a5=0,a6=0,a7=0;
  for (int p = rs; p < re; p += 8){
    int q = re - p;                          // >= 1, uniform
    int c0 = colb[p+0];                      // contiguous uniform loads (colb overallocated by 8)
    int c1 = colb[p+1]; int c2 = colb[p+2]; int c3 = colb[p+3];
    int c4 = colb[p+4]; int c5 = colb[p+5]; int c6 = colb[p+6]; int c7 = colb[p+7];
    c1 = (1 < q) ? c1 : c0;  c2 = (2 < q) ? c2 : c0;  c3 = (3 < q) ? c3 : c0;
    c4 = (4 < q) ? c4 : c0;  c5 = (5 < q) ? c5 : c0;  c6 = (6 < q) ? c6 : c0;
    c7 = (7 < q) ? c7 : c0;
    float x0 = hin[c0*64 + lane]; float x1 = hin[c1*64 + lane];
    float x2 = hin[c2*64 + lane]; float x3 = hin[c3*64 + lane];
    float x4 = hin[c4*64 + lane]; float x5 = hin[c5*64 + lane];
    float x6 = hin[c6*64 + lane]; float x7 = hin[c7*64 + lane];
    a0 += x0;
    a1 += (1 < q) ? x1 : 0.f;  a2 += (2 < q) ? x2 : 0.f;  a3 += (3 < q) ? x3 : 0.f;
    a4 += (4 < q) ? x4 : 0.f;  a5 += (5 < q) ? x5 : 0.f;  a6 += (6 < q) ? x6 : 0.f;
    a7 += (7 < q) ? x7 : 0.f;
  }
  acc += ((a0+a1)+(a2+a3)) + ((a4+a5)+(a6+a7));
  zout[i*64 + lane] = acc;
}

// ---------------- per-node MLP: z <- relu(z@W1+b1)@W2+b2, in place ----------------
// thread per node; weights via uniform s_load (SGPR operand of v_fmac);
// ReLU intermediate staged in LDS (pad 65 -> 2-way bank = free) to keep all
// register arrays compile-time indexed.
__global__ __launch_bounds__(192) void k_mlp(float* __restrict__ z,
                                             const float* __restrict__ w1, const float* __restrict__ b1,
                                             const float* __restrict__ w2, const float* __restrict__ b2, int n){
  __shared__ float tbuf[192*65];
  int node = blockIdx.x*192 + threadIdx.x;
  if (node >= n) return;
  float* zrow = z + (size_t)node*64;
  float acc[64];
  #pragma unroll
  for (int j = 0; j < 64; j++) acc[j] = b1[j];
  for (int kb = 0; kb < 16; ++kb){
    float4 c = *reinterpret_cast<const float4*>(zrow + kb*4);
    const float* wr = w1 + kb*256;           // rows 4kb..4kb+3 of W1
    #pragma unroll
    for (int j = 0; j < 64; j++)
      acc[j] += c.x*wr[j] + c.y*wr[64+j] + c.z*wr[128+j] + c.w*wr[192+j];
  }
  float* trow = tbuf + threadIdx.x*65;
  #pragma unroll
  for (int j = 0; j < 64; j++) trow[j] = fmaxf(acc[j], 0.f);
  #pragma unroll
  for (int j = 0; j < 64; j++) acc[j] = b2[j];
  for (int kb = 0; kb < 16; ++kb){
    float c0 = trow[kb*4+0], c1 = trow[kb*4+1], c2 = trow[kb*4+2], c3 = trow[kb*4+3];
    const float* wr = w2 + kb*256;
    #pragma unroll
    for (int j = 0; j < 64; j++)
      acc[j] += c0*wr[j] + c1*wr[64+j] + c2*wr[128+j] + c3*wr[192+j];
  }
  #pragma unroll
  for (int jb = 0; jb < 16; jb++)
    *reinterpret_cast<float4*>(zrow + jb*4) =
        make_float4(acc[jb*4], acc[jb*4+1], acc[jb*4+2], acc[jb*4+3]);
}

// ---------------- global_add_pool (batch is sorted) ----------------
__global__ __launch_bounds__(256) void k_pool(const float* __restrict__ h, const int* __restrict__ batch,
                                              float* __restrict__ g, int n, int ng){
  int wid  = __builtin_amdgcn_readfirstlane((int)(threadIdx.x >> 6));
  int lane = threadIdx.x & 63;
  int gi = blockIdx.x*4 + wid;
  if (gi >= ng) return;
  int lo = 0, hi = n;
  while (lo < hi){ int m = (lo + hi) >> 1; if (batch[m] < gi) lo = m + 1; else hi = m; }
  int s = lo;
  hi = n;
  while (lo < hi){ int m = (lo + hi) >> 1; if (batch[m] < gi + 1) lo = m + 1; else hi = m; }
  int t = lo;
  float a0=0,a1=0,a2=0,a3=0;
  for (int p = s; p < t; p += 4){
    a0 += h[(size_t)p*64 + lane];
    if (p+1 < t) a1 += h[(size_t)(p+1)*64 + lane];
    if (p+2 < t) a2 += h[(size_t)(p+2)*64 + lane];
    if (p+3 < t) a3 += h[(size_t)(p+3)*64 + lane];
  }
  g[(size_t)gi*64 + lane] = (a0+a1) + (a2+a3);
}

// ---------------- readout MLP 64->32->16->1 ----------------
__global__ __launch_bounds__(256) void k_readout(const float* __restrict__ g,
                                                 const float* __restrict__ w1, const float* __restrict__ b1,
                                                 const float* __restrict__ w2, const float* __restrict__ b2,
                                                 const float* __restrict__ w3, const float* __restrict__ b3,
                                                 float* __restrict__ out, int ng){
  int gi = blockIdx.x*256 + threadIdx.x;
  if (gi >= ng) return;
  const float* gr = g + (size_t)gi*64;
  float a1[32];
  #pragma unroll
  for (int j = 0; j < 32; j++) a1[j] = b1[j];
  for (int k = 0; k < 64; k++){
    float gv = gr[k];
    const float* wr = w1 + k*32;
    #pragma unroll
    for (int j = 0; j < 32; j++) a1[j] += gv * wr[j];
  }
  float a2[16];
  #pragma unroll
  for (int j = 0; j < 16; j++) a2[j] = b2[j];
  #pragma unroll
  for (int k = 0; k < 32; k++){
    float t = fmaxf(a1[k], 0.f);
    const float* wr = w2 + k*16;
    #pragma unroll
    for (int j = 0; j < 16; j++) a2[j] += t * wr[j];
  }
  float r = b3[0];
  #pragma unroll
  for (int k = 0; k < 16; k++) r += fmaxf(a2[k], 0.f) * w3[k];
  out[gi] = r;
}

extern "C" void kernel_launch(void* const* d_in, const int* in_sizes, int n_in,
                              void* d_out, int out_size, void* d_ws, size_t ws_size,
                              hipStream_t stream){
  const int N = N_NODES_C, E = N_EDGES_C, G = NUM_GRAPHS_C;
  const int*   x     = (const int*)d_in[0];
  const int*   ei    = (const int*)d_in[1];   // [2,E]: src = ei[0..E), dst = ei[E..2E)
  const int*   batch = (const int*)d_in[3];
  const float* nemb  = (const float*)d_in[4];
  const float* cw1   = (const float*)d_in[6];
  const float* cb1   = (const float*)d_in[7];
  const float* cw2   = (const float*)d_in[8];
  const float* cb2   = (const float*)d_in[9];
  const float* mw1   = (const float*)d_in[10];
  const float* mb1   = (const float*)d_in[11];
  const float* mw2   = (const float*)d_in[12];
  const float* mb2   = (const float*)d_in[13];
  const float* mw3   = (const float*)d_in[14];
  const float* mb3   = (const float*)d_in[15];
  float* out = (float*)d_out;

  char* cur = (char*)d_ws;
  auto take = [&](size_t bytes)->char*{
    char* p = cur; cur += (bytes + 255) & ~(size_t)255; return p;
  };
  const int NB = (N + 255)/256;                     // 782
  int*   deg    = (int*)  take((size_t)N*4);
  int*   fill   = (int*)  take((size_t)N*4);
  int*   tmp    = (int*)  take((size_t)N*4);
  int*   bsum   = (int*)  take((size_t)NB*4);
  int*   bofs   = (int*)  take((size_t)NB*4);
  int*   rowptr = (int*)  take((size_t)(N+1)*4);
  int*   colb   = (int*)  take((size_t)(E+8)*4);    // +8: safe overread in gather batching
  float* hA     = (float*)take((size_t)N*64*4);
  float* hB     = (float*)take((size_t)N*64*4);
  float* gbuf   = (float*)take((size_t)G*64*4);

  hipMemsetAsync(deg,  0, (size_t)N*4, stream);
  hipMemsetAsync(fill, 0, (size_t)N*4, stream);

  const int EB = (E + 255)/256;                     // 12500
  k_deg    <<<EB, 256, 0, stream>>>(ei + E, deg, E);
  k_scan1  <<<NB, 256, 0, stream>>>(deg, tmp, bsum, N);
  k_scan2  <<<1, 1024, 0, stream>>>(bsum, bofs, NB);
  k_scan3  <<<NB, 256, 0, stream>>>(tmp, bofs, rowptr, N);
  k_scatter<<<EB, 256, 0, stream>>>(ei, ei + E, rowptr, fill, colb, E);
  k_embed  <<<(N*64 + 255)/256, 256, 0, stream>>>(x, nemb, hA, N*64);

  float* A = hA; float* B = hB;
  for (int l = 0; l < 4; l++){
    k_gather<<<(N + 3)/4, 256, 0, stream>>>(A, rowptr, colb, B, N);
    k_mlp   <<<(N + 191)/192, 192, 0, stream>>>(B, cw1 + l*4096, cb1 + l*64,
                                                cw2 + l*4096, cb2 + l*64, N);
    float* t2 = A; A = B; B = t2;
  }
  k_pool   <<<(G + 3)/4, 256, 0, stream>>>(A, batch, gbuf, N, G);
  k_readout<<<(G + 255)/256, 256, 0, stream>>>(gbuf, mw1, mb1, mw2, mb2, mw3, mb3, out, G);
}